// Round 13
// baseline (255.046 us; speedup 1.0000x reference)
//
#include <hip/hip_runtime.h>
#include <math.h>

#define P_N 524288
#define NFRAMES 100
#define RESO_ 256
#define CHAN_ 64
#define NFREQ 10

// f32 transposed layout (fallback tiers): T[(f*3+pl)][t][x][c]
#define TROW   (RESO_ * CHAN_)          // 16384 floats per t-row
#define TPLANE (NFRAMES * TROW)         // 1,638,400 floats per plane

// fp16 transposed layout (main tier): row = 64 ch * 2B = 128 B = 1 line
#define T2PLANE_B ((size_t)NFRAMES * RESO_ * CHAN_ * 2)   // 3,276,800 B

#define NSUBS 64                        // independent sort blocks
#define SUBSZ (P_N / NSUBS)             // 8192 points per sub
#define NKEY (NFRAMES * 128)            // key = t*128 + (x0(cx)>>1)
#define NTRB  (3 * 3 * NFRAMES * 4)     // 3600 transpose blocks

// ---------------- fused prep: 64 per-sub LDS counting-sorts + transpose ----
template <typename TO, bool WXS>
__global__ __launch_bounds__(256) void prep5_k(const float* __restrict__ f0,
                                               const float* __restrict__ f1,
                                               const float* __restrict__ f2,
                                               TO* __restrict__ T,
                                               const float* __restrict__ xin,
                                               int* __restrict__ perm,
                                               float4* __restrict__ xs4) {
  __shared__ unsigned smem[NKEY];
  __shared__ unsigned part[257];

  if (blockIdx.x < NSUBS) {
    if (perm == nullptr) return;
    const int s = blockIdx.x;
    const float4* __restrict__ x4 = (const float4*)xin;
    for (int i = threadIdx.x; i < NKEY; i += 256) smem[i] = 0;
    __syncthreads();
    for (int i = threadIdx.x; i < SUBSZ; i += 256) {
      float4 v = x4[(size_t)s * SUBSZ + i];
      int t = min(max((int)v.w, 0), NFRAMES - 1);
      int x0 = min(max((int)floorf(v.x * 255.0f), 0), 254);
      atomicAdd(&smem[t * 128 + (x0 >> 1)], 1u);
    }
    __syncthreads();
    {
      const int tid = threadIdx.x;
      const int CH = NKEY / 256;         // 50
      unsigned vals[CH];
      unsigned loc = 0;
      #pragma unroll
      for (int i = 0; i < CH; i++) vals[i] = smem[tid * CH + i];
      for (int i = 0; i < CH; i++) { unsigned v = vals[i]; vals[i] = loc; loc += v; }
      part[tid] = loc;
      __syncthreads();
      if (tid == 0) {
        unsigned r = 0;
        for (int jj = 0; jj < 256; jj++) { unsigned v = part[jj]; part[jj] = r; r += v; }
      }
      __syncthreads();
      for (int i = 0; i < CH; i++) smem[tid * CH + i] = part[tid] + vals[i];
      __syncthreads();
    }
    for (int i = threadIdx.x; i < SUBSZ; i += 256) {
      float4 v = x4[(size_t)s * SUBSZ + i];
      int t = min(max((int)v.w, 0), NFRAMES - 1);
      int x0 = min(max((int)floorf(v.x * 255.0f), 0), 254);
      int pos = s * SUBSZ + (int)atomicAdd(&smem[t * 128 + (x0 >> 1)], 1u);
      perm[pos] = s * SUBSZ + i;
      if (WXS) xs4[pos] = v;
    }
    return;
  }

  // ---- transpose blocks (write TO: float or _Float16 RTN) ----
  float (*tile)[65] = (float(*)[65])smem;
  int b = blockIdx.x - NSUBS;
  int xblk = b & 3; b >>= 2;
  int t = b % NFRAMES; b /= NFRAMES;
  int pl = b % 3; int f = b / 3;
  const float* src = (f == 0 ? f0 : (f == 1 ? f1 : f2)) + (size_t)pl * CHAN_ * NFRAMES * RESO_;
  int lane = threadIdx.x & 63;
  int w = threadIdx.x >> 6;
  #pragma unroll
  for (int c = 0; c < 16; c++) {
    int cc = w * 16 + c;
    tile[cc][lane] = src[(size_t)cc * (NFRAMES * RESO_) + (size_t)t * RESO_ + xblk * 64 + lane];
  }
  __syncthreads();
  TO* dst = T + (((size_t)(f * 3 + pl) * NFRAMES + t) * RESO_ + (size_t)(xblk * 64)) * CHAN_;
  #pragma unroll
  for (int i = 0; i < 16; i++) {
    int xx = w * 16 + i;
    dst[(size_t)xx * CHAN_ + lane] = (TO)tile[lane][xx];
  }
}

__device__ __forceinline__ float hw_sin_rev(float rev) {
  float r, s;
  asm("v_fract_f32 %0, %1" : "=v"(r) : "v"(rev));
  asm("v_sin_f32 %0, %1" : "=v"(s) : "v"(r));
  return s;
}

// f32 = f16(lo/hi of packed dword) * f32 + f32, math in f32 (no cvt needed)
__device__ __forceinline__ float fma_mix_lo(unsigned h2, float b, float c) {
  float d;
  asm("v_fma_mix_f32 %0, %1, %2, %3 op_sel:[0,0,0] op_sel_hi:[1,0,0]"
      : "=v"(d) : "v"(h2), "v"(b), "v"(c));
  return d;
}
__device__ __forceinline__ float fma_mix_hi(unsigned h2, float b, float c) {
  float d;
  asm("v_fma_mix_f32 %0, %1, %2, %3 op_sel:[1,0,0] op_sel_hi:[1,0,0]"
      : "=v"(d) : "v"(h2), "v"(b), "v"(c));
  return d;
}

union U16x8 { uint4 u; unsigned d[4]; };

// 8 points per wave iteration: lane-group g = lane>>3 owns point k*8+g.
// Each 8-lane group loads a full 64-ch fp16 row as uint4 (128 B = 1 line).
// Lerp via v_fma_mix_f32 (f16 sources, f32 math). Lane-local PE: lane sl
// emits elements e = sl*8..sl*8+7 of its own group's point (no bpermute
// broadcast rounds).
__global__ __launch_bounds__(256) void sample8m_k(const float4* __restrict__ xs4,
                                                  const _Float16* __restrict__ T,
                                                  const int* __restrict__ perm,
                                                  float* __restrict__ out) {
  const int lane = threadIdx.x & 63;
  const int g = lane >> 3;          // group 0..7
  const int sl = lane & 7;          // sub-lane in group
  const int b = blockIdx.x;         // 4096 blocks
  const int wix = (b >> 3) * 4 + (threadIdx.x >> 6);   // 0..2047 within XCD
  const int q = (b & 7) * 32 + (wix >> 6);             // chunk 0..255 (~t)
  const int s = wix & 63;                              // sub 0..63
  const int base = s * SUBSZ + q * 32;                 // 32 points per wave

  const float inv2pi = 0.15915493667125702f;

  // per-lane PE table: element e = sl*8+i  (computed once; i is static)
  float smul[8], coff[8];
  int ddv[8], ovr[8], vld[8];
  #pragma unroll
  for (int i = 0; i < 8; i++) {
    int e = sl * 8 + i;
    vld[i] = (e < 63);
    if (e < 3) { ddv[i] = e; ovr[i] = 1; smul[i] = 0.0f; coff[i] = 0.0f; }
    else {
      int jj = e - 3;
      int f2 = jj / 6;
      int r2 = jj - f2 * 6;
      int is2 = r2 / 3;
      ddv[i] = r2 - is2 * 3;
      ovr[i] = 0;
      smul[i] = (float)(1 << f2) * inv2pi;
      coff[i] = is2 ? 0.25f : 0.0f;
    }
  }

  const char* Tb = (const char*)T;
  const int permv = perm[base + (lane & 31)];

  float4 c = xs4[base + g];

  #pragma unroll
  for (int k = 0; k < 4; k++) {
    // ---- weights + 3 column byte-offsets (fp16 layout) ----
    float tn = c.w * (1.0f / 99.0f);
    float gy = 2.0f * tn - 1.0f;
    float iy = ((gy + 1.0f) * 0.5f) * 99.0f;
    float y0f = floorf(iy);
    float wy1 = iy - y0f;
    int row; float wy;
    if (wy1 > 0.5f) { row = (int)y0f + 1; wy = wy1; }
    else            { row = (int)y0f;     wy = 1.0f - wy1; }
    row = min(max(row, 0), NFRAMES - 1);
    float wy3 = wy * wy * wy;
    const unsigned rowbyte = ((unsigned)row << 15) + ((unsigned)sl << 4);
    float wx[3]; unsigned cb[3];
    { float gx = 2.0f * c.x - 1.0f; float ix = ((gx + 1.0f) * 0.5f) * 255.0f;
      float x0f = floorf(ix); wx[0] = ix - x0f;
      cb[0] = rowbyte + ((unsigned)(int)x0f << 7); }
    { float gx = 2.0f * c.y - 1.0f; float ix = ((gx + 1.0f) * 0.5f) * 255.0f;
      float x0f = floorf(ix); wx[1] = ix - x0f;
      cb[1] = rowbyte + ((unsigned)(int)x0f << 7); }
    { float gx = 2.0f * c.z - 1.0f; float ix = ((gx + 1.0f) * 0.5f) * 255.0f;
      float x0f = floorf(ix); wx[2] = ix - x0f;
      cb[2] = rowbyte + ((unsigned)(int)x0f << 7); }

    // ---- 18 row loads (x0 and x0+1 rows per plane) ----
    U16x8 v0[9], v1[9];
    #pragma unroll
    for (int ss = 0; ss < 9; ss++) {
      const char* bp = Tb + (size_t)ss * T2PLANE_B;
      unsigned cbs = cb[ss % 3];
      v0[ss].u = *(const uint4*)(bp + cbs);
      v1[ss].u = *(const uint4*)(bp + cbs + 128);
    }
    float4 c_nxt = c;
    if (k < 3) c_nxt = xs4[base + (k + 1) * 8 + g];
    __builtin_amdgcn_sched_barrier(0);     // pin the load batch above

    // ---- consume: fma_mix lerp (f32 math, f16 srcs), product, 8-reduce ----
    float dsum[3];
    #pragma unroll
    for (int f = 0; f < 3; f++) {
      float pr[8];
      #pragma unroll
      for (int pl = 0; pl < 3; pl++) {
        int ss = f * 3 + pl;
        float w1 = wx[pl];
        float w0 = 1.0f - w1;
        #pragma unroll
        for (int dw = 0; dw < 4; dw++) {
          unsigned ad = v0[ss].d[dw];
          unsigned bd = v1[ss].d[dw];
          float slo = fma_mix_lo(ad, w0, fma_mix_lo(bd, w1, 0.0f));
          float shi = fma_mix_hi(ad, w0, fma_mix_hi(bd, w1, 0.0f));
          if (pl == 0) { pr[2 * dw] = slo;            pr[2 * dw + 1] = shi; }
          else         { pr[2 * dw] *= slo;           pr[2 * dw + 1] *= shi; }
        }
      }
      float r = (((pr[0] + pr[1]) + (pr[2] + pr[3])) +
                 ((pr[4] + pr[5]) + (pr[6] + pr[7]))) * wy3;
      #pragma unroll
      for (int m = 4; m > 0; m >>= 1) r += __shfl_xor(r, m, 64);  // 8-group
      dsum[f] = r;
    }

    float px = c.x + dsum[0];
    float py = c.y + dsum[1];
    float pz = c.z + dsum[2];

    // ---- lane-local PE + store: lane sl writes e = sl*8..sl*8+7 ----
    int pq = __shfl(permv, k * 8 + g, 64);
    float* op = out + (size_t)pq * 63 + sl * 8;
    #pragma unroll
    for (int i = 0; i < 8; i++) {
      float pd = (ddv[i] == 0) ? px : (ddv[i] == 1) ? py : pz;
      float val = hw_sin_rev(fmaf(pd, smul[i], coff[i]));
      if (ovr[i]) val = pd;
      if (vld[i]) __builtin_nontemporal_store(val, op + i);
    }

    c = c_nxt;
  }
}

// ---- fallback (ws fits f32 T only): 2-pt/wave, float2 channel pairs ----
__global__ __launch_bounds__(256) void sample2_k(const float* __restrict__ xin,
                                                 const float* __restrict__ T,
                                                 float* __restrict__ out) {
  const int lane = threadIdx.x & 63;
  const int half = lane >> 5;
  const int l = lane & 31;
  const int wave = blockIdx.x * 4 + (threadIdx.x >> 6);
  const int nW = gridDim.x * 4;
  const int j = (lane >= 3) ? (lane - 3) : 0;
  const int fq = j / 6;
  const int rr = j - fq * 6;
  const int isc = rr / 3;
  const int dd = rr - isc * 3;
  const float scale = (float)(1 << fq);
  const float cosoff = isc ? 0.25f : 0.0f;
  const float inv2pi = 0.15915493667125702f;
  const float4* __restrict__ x4 = (const float4*)xin;

  for (int base = wave * 2; base < P_N; base += nW * 2) {
    const int p = base + half;
    float4 c = x4[p];
    float tn = c.w / 99.0f;
    float gy = 2.0f * tn - 1.0f;
    float iy = ((gy + 1.0f) * 0.5f) * 99.0f;
    float y0f = floorf(iy);
    float wy1 = iy - y0f;
    int row; float wy;
    if (wy1 > 0.5f) { row = (int)y0f + 1; wy = wy1; }
    else            { row = (int)y0f;     wy = 1.0f - wy1; }
    row = min(max(row, 0), NFRAMES - 1);
    const int rowoff = row * TROW;
    float dsum[3];
    float crd[3] = {c.x, c.y, c.z};
    #pragma unroll
    for (int f = 0; f < 3; f++) {
      float prx, pry;
      #pragma unroll
      for (int pl = 0; pl < 3; pl++) {
        float gx = 2.0f * crd[pl] - 1.0f;
        float ix = ((gx + 1.0f) * 0.5f) * 255.0f;
        float x0f = floorf(ix);
        float wx1 = ix - x0f;
        float wx0 = 1.0f - wx1;
        int x0 = (int)x0f;
        const float2* rp = (const float2*)(T + (size_t)(f * 3 + pl) * TPLANE
                                             + (size_t)(rowoff + x0 * CHAN_));
        float2 v0 = rp[l];
        float2 v1 = rp[l + 32];
        float sx = (v0.x * wx0 + v1.x * wx1) * wy;
        float sy = (v0.y * wx0 + v1.y * wx1) * wy;
        if (pl == 0) { prx = sx; pry = sy; }
        else         { prx *= sx; pry *= sy; }
      }
      float r = prx + pry;
      #pragma unroll
      for (int m = 16; m > 0; m >>= 1) r += __shfl_xor(r, m, 64);
      dsum[f] = r;
    }
    float px = c.x + dsum[0];
    float py = c.y + dsum[1];
    float pz = c.z + dsum[2];
    #pragma unroll
    for (int qq = 0; qq < 2; qq++) {
      float qx = __shfl(px, qq * 32, 64);
      float qy = __shfl(py, qq * 32, 64);
      float qz = __shfl(pz, qq * 32, 64);
      float pd = (dd == 0) ? qx : (dd == 1) ? qy : qz;
      float val = hw_sin_rev(pd * scale * inv2pi + cosoff);
      if (lane == 0) val = qx;
      else if (lane == 1) val = qy;
      else if (lane == 2) val = qz;
      if (lane < 63) out[(size_t)(base + qq) * 63 + lane] = val;
    }
  }
}

// ---- fallback (no usable ws): direct-layout sampler ----
__global__ __launch_bounds__(256) void sample_fb_k(const float* __restrict__ xin,
                                                   const float* __restrict__ f0,
                                                   const float* __restrict__ f1,
                                                   const float* __restrict__ f2,
                                                   float* __restrict__ out) {
  const int lane = threadIdx.x & 63;
  int wave = blockIdx.x * 4 + (threadIdx.x >> 6);
  const int nW = gridDim.x * 4;
  for (int p = wave; p < P_N; p += nW) {
    float cx = xin[(size_t)p * 4 + 0];
    float cy = xin[(size_t)p * 4 + 1];
    float cz = xin[(size_t)p * 4 + 2];
    float ct = xin[(size_t)p * 4 + 3];
    float tn = ct / 99.0f;
    float gy = 2.0f * tn - 1.0f;
    float iy = ((gy + 1.0f) * 0.5f) * 99.0f;
    float y0f = floorf(iy);
    float wy1 = iy - y0f;
    float wy0 = 1.0f - wy1;
    int y0 = (int)y0f, y1 = y0 + 1;
    bool y0in = (unsigned)y0 < (unsigned)NFRAMES;
    bool y1in = (unsigned)y1 < (unsigned)NFRAMES;
    int y0c = min(max(y0, 0), NFRAMES - 1);
    int y1c = min(max(y1, 0), NFRAMES - 1);
    float d[3];
    #pragma unroll
    for (int f = 0; f < 3; f++) {
      float prodc;
      #pragma unroll
      for (int pl = 0; pl < 3; pl++) {
        float coord = (pl == 0) ? cx : (pl == 1) ? cy : cz;
        float gx = 2.0f * coord - 1.0f;
        float ix = ((gx + 1.0f) * 0.5f) * 255.0f;
        float x0f = floorf(ix);
        float wx1 = ix - x0f;
        float wx0 = 1.0f - wx1;
        int x0 = (int)x0f, x1 = x0 + 1;
        int x0c = min(max(x0, 0), RESO_ - 1);
        int x1c = min(max(x1, 0), RESO_ - 1);
        const float* ff = (f == 0) ? f0 : (f == 1) ? f1 : f2;
        const float* bse = ff + ((size_t)pl * CHAN_ + lane) * (NFRAMES * RESO_);
        float v00 = y0in ? bse[(size_t)y0c * RESO_ + x0c] : 0.0f;
        float v01 = y0in ? bse[(size_t)y0c * RESO_ + x1c] : 0.0f;
        float v10 = y1in ? bse[(size_t)y1c * RESO_ + x0c] : 0.0f;
        float v11 = y1in ? bse[(size_t)y1c * RESO_ + x1c] : 0.0f;
        float ss2 = v00 * (wy0 * wx0) + v01 * (wy0 * wx1) + v10 * (wy1 * wx0) + v11 * (wy1 * wx1);
        prodc = (pl == 0) ? ss2 : prodc * ss2;
      }
      float sum = prodc;
      #pragma unroll
      for (int o = 32; o > 0; o >>= 1) sum += __shfl_xor(sum, o, 64);
      d[f] = sum;
    }
    float p0 = cx + d[0], p1 = cy + d[1], p2 = cz + d[2];
    if (lane < 63) {
      float val;
      if (lane == 0) val = p0;
      else if (lane == 1) val = p1;
      else if (lane == 2) val = p2;
      else {
        int jj = lane - 3;
        int fq2 = jj / 6;
        int r2 = jj - fq2 * 6;
        int s2 = r2 / 3;
        int d2 = r2 - s2 * 3;
        float pd = (d2 == 0) ? p0 : (d2 == 1) ? p1 : p2;
        float ang = pd * (float)(1 << fq2);
        val = (s2 == 0) ? sinf(ang) : cosf(ang);
      }
      out[(size_t)p * 63 + lane] = val;
    }
  }
}

extern "C" void kernel_launch(void* const* d_in, const int* in_sizes, int n_in,
                              void* d_out, int out_size, void* d_ws, size_t ws_size,
                              hipStream_t stream) {
  const float* x  = (const float*)d_in[0];
  const float* f0 = (const float*)d_in[1];
  const float* f1 = (const float*)d_in[2];
  const float* f2 = (const float*)d_in[3];
  float* out = (float*)d_out;

  const size_t szT2   = (size_t)9 * T2PLANE_B;                  // ~29.5 MB
  const size_t szT    = (size_t)9 * TPLANE * sizeof(float);     // ~59 MB
  const size_t szPerm = (size_t)P_N * sizeof(int);              // 2 MB
  const size_t szXs   = (size_t)P_N * sizeof(float4);           // 8 MB

  if (ws_size >= szT2 + szPerm + szXs) {
    _Float16* T2 = (_Float16*)d_ws;
    int* perm    = (int*)((char*)d_ws + szT2);
    float4* xs4  = (float4*)((char*)d_ws + szT2 + szPerm);
    prep5_k<_Float16, true><<<dim3(NSUBS + NTRB), dim3(256), 0, stream>>>(
        f0, f1, f2, T2, x, perm, xs4);
    sample8m_k<<<dim3(4096), dim3(256), 0, stream>>>(xs4, T2, perm, out);
  } else if (ws_size >= szT) {
    float* T = (float*)d_ws;
    prep5_k<float, false><<<dim3(NSUBS + NTRB), dim3(256), 0, stream>>>(
        f0, f1, f2, T, x, nullptr, nullptr);
    sample2_k<<<dim3(4096), dim3(256), 0, stream>>>(x, T, out);
  } else {
    sample_fb_k<<<dim3(8192), dim3(256), 0, stream>>>(x, f0, f1, f2, out);
  }
}

// Round 14
// 122.059 us; speedup vs baseline: 2.0895x; 2.0895x over previous
//
#include <hip/hip_runtime.h>
#include <math.h>

#define P_N 524288
#define NFRAMES 100
#define RESO_ 256
#define CHAN_ 64
#define NFREQ 10

// f32 transposed layout (fallback tiers): T[(f*3+pl)][t][x][c]
#define TROW   (RESO_ * CHAN_)          // 16384 floats per t-row
#define TPLANE (NFRAMES * TROW)         // 1,638,400 floats per plane

// fp16 transposed layout (main tier): row = 64 ch * 2B = 128 B = 1 line
#define T2PLANE_B ((size_t)NFRAMES * RESO_ * CHAN_ * 2)   // 3,276,800 B

#define NSUBS 64                        // independent sort blocks
#define SUBSZ (P_N / NSUBS)             // 8192 points per sub
#define NKEY (NFRAMES * 128)            // key = t*128 + (x0(cx)>>1)
#define NTRB  (3 * 3 * NFRAMES * 4)     // 3600 transpose blocks

// ---------------- fused prep: 64 per-sub LDS counting-sorts + transpose ----
template <typename TO, bool WXS>
__global__ __launch_bounds__(256) void prep5_k(const float* __restrict__ f0,
                                               const float* __restrict__ f1,
                                               const float* __restrict__ f2,
                                               TO* __restrict__ T,
                                               const float* __restrict__ xin,
                                               int* __restrict__ perm,
                                               float4* __restrict__ xs4) {
  __shared__ unsigned smem[NKEY];
  __shared__ unsigned part[257];

  if (blockIdx.x < NSUBS) {
    if (perm == nullptr) return;
    const int s = blockIdx.x;
    const float4* __restrict__ x4 = (const float4*)xin;
    for (int i = threadIdx.x; i < NKEY; i += 256) smem[i] = 0;
    __syncthreads();
    for (int i = threadIdx.x; i < SUBSZ; i += 256) {
      float4 v = x4[(size_t)s * SUBSZ + i];
      int t = min(max((int)v.w, 0), NFRAMES - 1);
      int x0 = min(max((int)floorf(v.x * 255.0f), 0), 254);
      atomicAdd(&smem[t * 128 + (x0 >> 1)], 1u);
    }
    __syncthreads();
    {
      const int tid = threadIdx.x;
      const int CH = NKEY / 256;         // 50
      unsigned vals[CH];
      unsigned loc = 0;
      #pragma unroll
      for (int i = 0; i < CH; i++) vals[i] = smem[tid * CH + i];
      for (int i = 0; i < CH; i++) { unsigned v = vals[i]; vals[i] = loc; loc += v; }
      part[tid] = loc;
      __syncthreads();
      if (tid == 0) {
        unsigned r = 0;
        for (int jj = 0; jj < 256; jj++) { unsigned v = part[jj]; part[jj] = r; r += v; }
      }
      __syncthreads();
      for (int i = 0; i < CH; i++) smem[tid * CH + i] = part[tid] + vals[i];
      __syncthreads();
    }
    for (int i = threadIdx.x; i < SUBSZ; i += 256) {
      float4 v = x4[(size_t)s * SUBSZ + i];
      int t = min(max((int)v.w, 0), NFRAMES - 1);
      int x0 = min(max((int)floorf(v.x * 255.0f), 0), 254);
      int pos = s * SUBSZ + (int)atomicAdd(&smem[t * 128 + (x0 >> 1)], 1u);
      perm[pos] = s * SUBSZ + i;
      if (WXS) xs4[pos] = v;
    }
    return;
  }

  // ---- transpose blocks (write TO: float or _Float16 RTN) ----
  float (*tile)[65] = (float(*)[65])smem;
  int b = blockIdx.x - NSUBS;
  int xblk = b & 3; b >>= 2;
  int t = b % NFRAMES; b /= NFRAMES;
  int pl = b % 3; int f = b / 3;
  const float* src = (f == 0 ? f0 : (f == 1 ? f1 : f2)) + (size_t)pl * CHAN_ * NFRAMES * RESO_;
  int lane = threadIdx.x & 63;
  int w = threadIdx.x >> 6;
  #pragma unroll
  for (int c = 0; c < 16; c++) {
    int cc = w * 16 + c;
    tile[cc][lane] = src[(size_t)cc * (NFRAMES * RESO_) + (size_t)t * RESO_ + xblk * 64 + lane];
  }
  __syncthreads();
  TO* dst = T + (((size_t)(f * 3 + pl) * NFRAMES + t) * RESO_ + (size_t)(xblk * 64)) * CHAN_;
  #pragma unroll
  for (int i = 0; i < 16; i++) {
    int xx = w * 16 + i;
    dst[(size_t)xx * CHAN_ + lane] = (TO)tile[lane][xx];
  }
}

__device__ __forceinline__ float hw_sin_rev(float rev) {
  float r, s;
  asm("v_fract_f32 %0, %1" : "=v"(r) : "v"(rev));
  asm("v_sin_f32 %0, %1" : "=v"(s) : "v"(r));
  return s;
}

// f32 = f16(lo/hi half of packed dword) * f32 + f32 — f32 math, no cvt
__device__ __forceinline__ float fma_mix_lo(unsigned h2, float b, float c) {
  float d;
  asm("v_fma_mix_f32 %0, %1, %2, %3 op_sel:[0,0,0] op_sel_hi:[1,0,0]"
      : "=v"(d) : "v"(h2), "v"(b), "v"(c));
  return d;
}
__device__ __forceinline__ float fma_mix_hi(unsigned h2, float b, float c) {
  float d;
  asm("v_fma_mix_f32 %0, %1, %2, %3 op_sel:[1,0,0] op_sel_hi:[1,0,0]"
      : "=v"(d) : "v"(h2), "v"(b), "v"(c));
  return d;
}

union U16x8 { uint4 u; unsigned d[4]; };

// 8 points per wave iteration: lane-group g = lane>>3 owns point k*8+g.
// Each 8-lane group loads a full 64-ch fp16 row as uint4 (128 B = 1 line).
// Lerp via v_fma_mix_f32; PE/store = R12's broadcast structure (8 rounds,
// all 63 lanes store one point's row contiguously — store-coalescing is
// worth more than PE lane-efficiency; R13 lesson).
__global__ __launch_bounds__(256) void sample8h_k(const float4* __restrict__ xs4,
                                                  const _Float16* __restrict__ T,
                                                  const int* __restrict__ perm,
                                                  float* __restrict__ out) {
  const int lane = threadIdx.x & 63;
  const int g = lane >> 3;          // group 0..7
  const int sl = lane & 7;          // sub-lane in group
  const int b = blockIdx.x;         // 4096 blocks
  const int wix = (b >> 3) * 4 + (threadIdx.x >> 6);   // 0..2047 within XCD
  const int q = (b & 7) * 32 + (wix >> 6);             // chunk 0..255 (~t)
  const int s = wix & 63;                              // sub 0..63
  const int base = s * SUBSZ + q * 32;                 // 32 points per wave

  // per-lane PE constants (output element id = lane, valid for lane<63)
  const int j = (lane >= 3) ? (lane - 3) : 0;
  const int fq = j / 6;
  const int rr = j - fq * 6;
  const int isc = rr / 3;
  const int dd = rr - isc * 3;
  const float scale = (float)(1 << fq);
  const float cosoff = isc ? 0.25f : 0.0f;
  const float inv2pi = 0.15915493667125702f;

  const char* Tb = (const char*)T;
  const int permv = perm[base + (lane & 31)];

  float4 c = xs4[base + g];

  #pragma unroll
  for (int k = 0; k < 4; k++) {
    // ---- weights + 3 column byte-offsets (fp16 layout) ----
    float tn = c.w * (1.0f / 99.0f);
    float gy = 2.0f * tn - 1.0f;
    float iy = ((gy + 1.0f) * 0.5f) * 99.0f;
    float y0f = floorf(iy);
    float wy1 = iy - y0f;
    int row; float wy;
    if (wy1 > 0.5f) { row = (int)y0f + 1; wy = wy1; }
    else            { row = (int)y0f;     wy = 1.0f - wy1; }
    row = min(max(row, 0), NFRAMES - 1);
    float wy3 = wy * wy * wy;
    const unsigned rowbyte = ((unsigned)row << 15) + ((unsigned)sl << 4);
    float wx[3]; unsigned cb[3];
    { float gx = 2.0f * c.x - 1.0f; float ix = ((gx + 1.0f) * 0.5f) * 255.0f;
      float x0f = floorf(ix); wx[0] = ix - x0f;
      cb[0] = rowbyte + ((unsigned)(int)x0f << 7); }
    { float gx = 2.0f * c.y - 1.0f; float ix = ((gx + 1.0f) * 0.5f) * 255.0f;
      float x0f = floorf(ix); wx[1] = ix - x0f;
      cb[1] = rowbyte + ((unsigned)(int)x0f << 7); }
    { float gx = 2.0f * c.z - 1.0f; float ix = ((gx + 1.0f) * 0.5f) * 255.0f;
      float x0f = floorf(ix); wx[2] = ix - x0f;
      cb[2] = rowbyte + ((unsigned)(int)x0f << 7); }

    // ---- 18 row loads (x0 and x0+1 rows per plane) ----
    U16x8 v0[9], v1[9];
    #pragma unroll
    for (int ss = 0; ss < 9; ss++) {
      const char* bp = Tb + (size_t)ss * T2PLANE_B;
      unsigned cbs = cb[ss % 3];
      v0[ss].u = *(const uint4*)(bp + cbs);
      v1[ss].u = *(const uint4*)(bp + cbs + 128);
    }
    float4 c_nxt = c;
    if (k < 3) c_nxt = xs4[base + (k + 1) * 8 + g];
    __builtin_amdgcn_sched_barrier(0);     // pin the load batch above

    // ---- consume: fma_mix lerp (f32 math, f16 srcs), product, 8-reduce ----
    float dsum[3];
    #pragma unroll
    for (int f = 0; f < 3; f++) {
      float pr[8];
      #pragma unroll
      for (int pl = 0; pl < 3; pl++) {
        int ss = f * 3 + pl;
        float w1 = wx[pl];
        float w0 = 1.0f - w1;
        #pragma unroll
        for (int dw = 0; dw < 4; dw++) {
          unsigned ad = v0[ss].d[dw];
          unsigned bd = v1[ss].d[dw];
          float slo = fma_mix_lo(ad, w0, fma_mix_lo(bd, w1, 0.0f));
          float shi = fma_mix_hi(ad, w0, fma_mix_hi(bd, w1, 0.0f));
          if (pl == 0) { pr[2 * dw] = slo;  pr[2 * dw + 1] = shi; }
          else         { pr[2 * dw] *= slo; pr[2 * dw + 1] *= shi; }
        }
      }
      float r = (((pr[0] + pr[1]) + (pr[2] + pr[3])) +
                 ((pr[4] + pr[5]) + (pr[6] + pr[7]))) * wy3;
      #pragma unroll
      for (int m = 4; m > 0; m >>= 1) r += __shfl_xor(r, m, 64);  // 8-group
      dsum[f] = r;
    }

    float px = c.x + dsum[0];
    float py = c.y + dsum[1];
    float pz = c.z + dsum[2];

    // ---- PE + store: 8 rounds, one point each (coalesced 252 B store) ----
    #pragma unroll
    for (int q2 = 0; q2 < 8; q2++) {
      float qx = __shfl(px, q2 * 8, 64);
      float qy = __shfl(py, q2 * 8, 64);
      float qz = __shfl(pz, q2 * 8, 64);
      int pq = __shfl(permv, k * 8 + q2, 64);
      float pd = (dd == 0) ? qx : (dd == 1) ? qy : qz;
      float val = hw_sin_rev(pd * scale * inv2pi + cosoff);
      if (lane == 0) val = qx;
      else if (lane == 1) val = qy;
      else if (lane == 2) val = qz;
      if (lane < 63)
        __builtin_nontemporal_store(val, &out[(size_t)pq * 63 + lane]);
    }

    c = c_nxt;
  }
}

// ---- fallback (ws fits f32 T only): 2-pt/wave, float2 channel pairs ----
__global__ __launch_bounds__(256) void sample2_k(const float* __restrict__ xin,
                                                 const float* __restrict__ T,
                                                 float* __restrict__ out) {
  const int lane = threadIdx.x & 63;
  const int half = lane >> 5;
  const int l = lane & 31;
  const int wave = blockIdx.x * 4 + (threadIdx.x >> 6);
  const int nW = gridDim.x * 4;
  const int j = (lane >= 3) ? (lane - 3) : 0;
  const int fq = j / 6;
  const int rr = j - fq * 6;
  const int isc = rr / 3;
  const int dd = rr - isc * 3;
  const float scale = (float)(1 << fq);
  const float cosoff = isc ? 0.25f : 0.0f;
  const float inv2pi = 0.15915493667125702f;
  const float4* __restrict__ x4 = (const float4*)xin;

  for (int base = wave * 2; base < P_N; base += nW * 2) {
    const int p = base + half;
    float4 c = x4[p];
    float tn = c.w / 99.0f;
    float gy = 2.0f * tn - 1.0f;
    float iy = ((gy + 1.0f) * 0.5f) * 99.0f;
    float y0f = floorf(iy);
    float wy1 = iy - y0f;
    int row; float wy;
    if (wy1 > 0.5f) { row = (int)y0f + 1; wy = wy1; }
    else            { row = (int)y0f;     wy = 1.0f - wy1; }
    row = min(max(row, 0), NFRAMES - 1);
    const int rowoff = row * TROW;
    float dsum[3];
    float crd[3] = {c.x, c.y, c.z};
    #pragma unroll
    for (int f = 0; f < 3; f++) {
      float prx, pry;
      #pragma unroll
      for (int pl = 0; pl < 3; pl++) {
        float gx = 2.0f * crd[pl] - 1.0f;
        float ix = ((gx + 1.0f) * 0.5f) * 255.0f;
        float x0f = floorf(ix);
        float wx1 = ix - x0f;
        float wx0 = 1.0f - wx1;
        int x0 = (int)x0f;
        const float2* rp = (const float2*)(T + (size_t)(f * 3 + pl) * TPLANE
                                             + (size_t)(rowoff + x0 * CHAN_));
        float2 v0 = rp[l];
        float2 v1 = rp[l + 32];
        float sx = (v0.x * wx0 + v1.x * wx1) * wy;
        float sy = (v0.y * wx0 + v1.y * wx1) * wy;
        if (pl == 0) { prx = sx; pry = sy; }
        else         { prx *= sx; pry *= sy; }
      }
      float r = prx + pry;
      #pragma unroll
      for (int m = 16; m > 0; m >>= 1) r += __shfl_xor(r, m, 64);
      dsum[f] = r;
    }
    float px = c.x + dsum[0];
    float py = c.y + dsum[1];
    float pz = c.z + dsum[2];
    #pragma unroll
    for (int qq = 0; qq < 2; qq++) {
      float qx = __shfl(px, qq * 32, 64);
      float qy = __shfl(py, qq * 32, 64);
      float qz = __shfl(pz, qq * 32, 64);
      float pd = (dd == 0) ? qx : (dd == 1) ? qy : qz;
      float val = hw_sin_rev(pd * scale * inv2pi + cosoff);
      if (lane == 0) val = qx;
      else if (lane == 1) val = qy;
      else if (lane == 2) val = qz;
      if (lane < 63) out[(size_t)(base + qq) * 63 + lane] = val;
    }
  }
}

// ---- fallback (no usable ws): direct-layout sampler ----
__global__ __launch_bounds__(256) void sample_fb_k(const float* __restrict__ xin,
                                                   const float* __restrict__ f0,
                                                   const float* __restrict__ f1,
                                                   const float* __restrict__ f2,
                                                   float* __restrict__ out) {
  const int lane = threadIdx.x & 63;
  int wave = blockIdx.x * 4 + (threadIdx.x >> 6);
  const int nW = gridDim.x * 4;
  for (int p = wave; p < P_N; p += nW) {
    float cx = xin[(size_t)p * 4 + 0];
    float cy = xin[(size_t)p * 4 + 1];
    float cz = xin[(size_t)p * 4 + 2];
    float ct = xin[(size_t)p * 4 + 3];
    float tn = ct / 99.0f;
    float gy = 2.0f * tn - 1.0f;
    float iy = ((gy + 1.0f) * 0.5f) * 99.0f;
    float y0f = floorf(iy);
    float wy1 = iy - y0f;
    float wy0 = 1.0f - wy1;
    int y0 = (int)y0f, y1 = y0 + 1;
    bool y0in = (unsigned)y0 < (unsigned)NFRAMES;
    bool y1in = (unsigned)y1 < (unsigned)NFRAMES;
    int y0c = min(max(y0, 0), NFRAMES - 1);
    int y1c = min(max(y1, 0), NFRAMES - 1);
    float d[3];
    #pragma unroll
    for (int f = 0; f < 3; f++) {
      float prodc;
      #pragma unroll
      for (int pl = 0; pl < 3; pl++) {
        float coord = (pl == 0) ? cx : (pl == 1) ? cy : cz;
        float gx = 2.0f * coord - 1.0f;
        float ix = ((gx + 1.0f) * 0.5f) * 255.0f;
        float x0f = floorf(ix);
        float wx1 = ix - x0f;
        float wx0 = 1.0f - wx1;
        int x0 = (int)x0f, x1 = x0 + 1;
        int x0c = min(max(x0, 0), RESO_ - 1);
        int x1c = min(max(x1, 0), RESO_ - 1);
        const float* ff = (f == 0) ? f0 : (f == 1) ? f1 : f2;
        const float* bse = ff + ((size_t)pl * CHAN_ + lane) * (NFRAMES * RESO_);
        float v00 = y0in ? bse[(size_t)y0c * RESO_ + x0c] : 0.0f;
        float v01 = y0in ? bse[(size_t)y0c * RESO_ + x1c] : 0.0f;
        float v10 = y1in ? bse[(size_t)y1c * RESO_ + x0c] : 0.0f;
        float v11 = y1in ? bse[(size_t)y1c * RESO_ + x1c] : 0.0f;
        float ss2 = v00 * (wy0 * wx0) + v01 * (wy0 * wx1) + v10 * (wy1 * wx0) + v11 * (wy1 * wx1);
        prodc = (pl == 0) ? ss2 : prodc * ss2;
      }
      float sum = prodc;
      #pragma unroll
      for (int o = 32; o > 0; o >>= 1) sum += __shfl_xor(sum, o, 64);
      d[f] = sum;
    }
    float p0 = cx + d[0], p1 = cy + d[1], p2 = cz + d[2];
    if (lane < 63) {
      float val;
      if (lane == 0) val = p0;
      else if (lane == 1) val = p1;
      else if (lane == 2) val = p2;
      else {
        int jj = lane - 3;
        int fq2 = jj / 6;
        int r2 = jj - fq2 * 6;
        int s2 = r2 / 3;
        int d2 = r2 - s2 * 3;
        float pd = (d2 == 0) ? p0 : (d2 == 1) ? p1 : p2;
        float ang = pd * (float)(1 << fq2);
        val = (s2 == 0) ? sinf(ang) : cosf(ang);
      }
      out[(size_t)p * 63 + lane] = val;
    }
  }
}

extern "C" void kernel_launch(void* const* d_in, const int* in_sizes, int n_in,
                              void* d_out, int out_size, void* d_ws, size_t ws_size,
                              hipStream_t stream) {
  const float* x  = (const float*)d_in[0];
  const float* f0 = (const float*)d_in[1];
  const float* f1 = (const float*)d_in[2];
  const float* f2 = (const float*)d_in[3];
  float* out = (float*)d_out;

  const size_t szT2   = (size_t)9 * T2PLANE_B;                  // ~29.5 MB
  const size_t szT    = (size_t)9 * TPLANE * sizeof(float);     // ~59 MB
  const size_t szPerm = (size_t)P_N * sizeof(int);              // 2 MB
  const size_t szXs   = (size_t)P_N * sizeof(float4);           // 8 MB

  if (ws_size >= szT2 + szPerm + szXs) {
    _Float16* T2 = (_Float16*)d_ws;
    int* perm    = (int*)((char*)d_ws + szT2);
    float4* xs4  = (float4*)((char*)d_ws + szT2 + szPerm);
    prep5_k<_Float16, true><<<dim3(NSUBS + NTRB), dim3(256), 0, stream>>>(
        f0, f1, f2, T2, x, perm, xs4);
    sample8h_k<<<dim3(4096), dim3(256), 0, stream>>>(xs4, T2, perm, out);
  } else if (ws_size >= szT) {
    float* T = (float*)d_ws;
    prep5_k<float, false><<<dim3(NSUBS + NTRB), dim3(256), 0, stream>>>(
        f0, f1, f2, T, x, nullptr, nullptr);
    sample2_k<<<dim3(4096), dim3(256), 0, stream>>>(x, T, out);
  } else {
    sample_fb_k<<<dim3(8192), dim3(256), 0, stream>>>(x, f0, f1, f2, out);
  }
}

// Round 15
// 117.964 us; speedup vs baseline: 2.1621x; 1.0347x over previous
//
#include <hip/hip_runtime.h>
#include <math.h>

#define P_N 524288
#define NFRAMES 100
#define RESO_ 256
#define CHAN_ 64
#define NFREQ 10

// f32 transposed layout (fallback tiers): T[(f*3+pl)][t][x][c]
#define TROW   (RESO_ * CHAN_)          // 16384 floats per t-row
#define TPLANE (NFRAMES * TROW)         // 1,638,400 floats per plane

// fp16 transposed layout (main tier): row = 64 ch * 2B = 128 B = 1 line
#define T2PLANE_B ((size_t)NFRAMES * RESO_ * CHAN_ * 2)   // 3,276,800 B

#define NSUBS 64                        // independent sort blocks
#define SUBSZ (P_N / NSUBS)             // 8192 points per sub
#define NKEY (NFRAMES * 128)            // key = t*128 + (x0(cx)>>1)
#define NTRB  (3 * 3 * NFRAMES * 4)     // 3600 transpose blocks

// ---------------- fused prep: 64 per-sub LDS counting-sorts + transpose ----
template <typename TO, bool WXS>
__global__ __launch_bounds__(256) void prep5_k(const float* __restrict__ f0,
                                               const float* __restrict__ f1,
                                               const float* __restrict__ f2,
                                               TO* __restrict__ T,
                                               const float* __restrict__ xin,
                                               int* __restrict__ perm,
                                               float4* __restrict__ xs4) {
  __shared__ unsigned smem[NKEY];
  __shared__ unsigned part[257];

  if (blockIdx.x < NSUBS) {
    if (perm == nullptr) return;
    const int s = blockIdx.x;
    const float4* __restrict__ x4 = (const float4*)xin;
    for (int i = threadIdx.x; i < NKEY; i += 256) smem[i] = 0;
    __syncthreads();
    for (int i = threadIdx.x; i < SUBSZ; i += 256) {
      float4 v = x4[(size_t)s * SUBSZ + i];
      int t = min(max((int)v.w, 0), NFRAMES - 1);
      int x0 = min(max((int)floorf(v.x * 255.0f), 0), 254);
      atomicAdd(&smem[t * 128 + (x0 >> 1)], 1u);
    }
    __syncthreads();
    {
      const int tid = threadIdx.x;
      const int CH = NKEY / 256;         // 50
      unsigned vals[CH];
      unsigned loc = 0;
      #pragma unroll
      for (int i = 0; i < CH; i++) vals[i] = smem[tid * CH + i];
      for (int i = 0; i < CH; i++) { unsigned v = vals[i]; vals[i] = loc; loc += v; }
      part[tid] = loc;
      __syncthreads();
      if (tid == 0) {
        unsigned r = 0;
        for (int jj = 0; jj < 256; jj++) { unsigned v = part[jj]; part[jj] = r; r += v; }
      }
      __syncthreads();
      for (int i = 0; i < CH; i++) smem[tid * CH + i] = part[tid] + vals[i];
      __syncthreads();
    }
    for (int i = threadIdx.x; i < SUBSZ; i += 256) {
      float4 v = x4[(size_t)s * SUBSZ + i];
      int t = min(max((int)v.w, 0), NFRAMES - 1);
      int x0 = min(max((int)floorf(v.x * 255.0f), 0), 254);
      int pos = s * SUBSZ + (int)atomicAdd(&smem[t * 128 + (x0 >> 1)], 1u);
      perm[pos] = s * SUBSZ + i;
      if (WXS) xs4[pos] = v;
    }
    return;
  }

  // ---- transpose blocks (write TO: float or _Float16 RTN) ----
  float (*tile)[65] = (float(*)[65])smem;
  int b = blockIdx.x - NSUBS;
  int xblk = b & 3; b >>= 2;
  int t = b % NFRAMES; b /= NFRAMES;
  int pl = b % 3; int f = b / 3;
  const float* src = (f == 0 ? f0 : (f == 1 ? f1 : f2)) + (size_t)pl * CHAN_ * NFRAMES * RESO_;
  int lane = threadIdx.x & 63;
  int w = threadIdx.x >> 6;
  #pragma unroll
  for (int c = 0; c < 16; c++) {
    int cc = w * 16 + c;
    tile[cc][lane] = src[(size_t)cc * (NFRAMES * RESO_) + (size_t)t * RESO_ + xblk * 64 + lane];
  }
  __syncthreads();
  TO* dst = T + (((size_t)(f * 3 + pl) * NFRAMES + t) * RESO_ + (size_t)(xblk * 64)) * CHAN_;
  #pragma unroll
  for (int i = 0; i < 16; i++) {
    int xx = w * 16 + i;
    dst[(size_t)xx * CHAN_ + lane] = (TO)tile[lane][xx];
  }
}

__device__ __forceinline__ float hw_sin_rev(float rev) {
  float r, s;
  asm("v_fract_f32 %0, %1" : "=v"(r) : "v"(rev));
  asm("v_sin_f32 %0, %1" : "=v"(s) : "v"(r));
  return s;
}

// f32 = f16(lo/hi half of packed dword) * f32 + f32 — f32 math, no cvt
__device__ __forceinline__ float fma_mix_lo(unsigned h2, float b, float c) {
  float d;
  asm("v_fma_mix_f32 %0, %1, %2, %3 op_sel:[0,0,0] op_sel_hi:[1,0,0]"
      : "=v"(d) : "v"(h2), "v"(b), "v"(c));
  return d;
}
__device__ __forceinline__ float fma_mix_hi(unsigned h2, float b, float c) {
  float d;
  asm("v_fma_mix_f32 %0, %1, %2, %3 op_sel:[1,0,0] op_sel_hi:[1,0,0]"
      : "=v"(d) : "v"(h2), "v"(b), "v"(c));
  return d;
}

union U16x8 { uint4 u; unsigned d[4]; };

// 8 points per wave iteration, 16 points per wave (2 iters); 8192 blocks ->
// 32768 waves = 8 waves/SIMD ceiling (R14 was grid-limited at 4/SIMD).
// Each 8-lane group loads a full 64-ch fp16 row as uint4 (128 B = 1 line).
// Lerp via v_fma_mix_f32; PE/store = broadcast structure (coalesced 252 B).
__global__ __launch_bounds__(256) void sample8h_k(const float4* __restrict__ xs4,
                                                  const _Float16* __restrict__ T,
                                                  const int* __restrict__ perm,
                                                  float* __restrict__ out) {
  const int lane = threadIdx.x & 63;
  const int g = lane >> 3;          // group 0..7
  const int sl = lane & 7;          // sub-lane in group
  const int b = blockIdx.x;         // 8192 blocks
  const int wix = (b >> 3) * 4 + (threadIdx.x >> 6);   // 0..4095 within XCD
  const int q = (b & 7) * 64 + (wix >> 6);             // chunk 0..511 (~t)
  const int s = wix & 63;                              // sub 0..63
  const int base = s * SUBSZ + q * 16;                 // 16 points per wave

  // per-lane PE constants (output element id = lane, valid for lane<63)
  const int j = (lane >= 3) ? (lane - 3) : 0;
  const int fq = j / 6;
  const int rr = j - fq * 6;
  const int isc = rr / 3;
  const int dd = rr - isc * 3;
  const float scale = (float)(1 << fq);
  const float cosoff = isc ? 0.25f : 0.0f;
  const float inv2pi = 0.15915493667125702f;

  const char* Tb = (const char*)T;
  const int permv = perm[base + (lane & 15)];

  float4 c = xs4[base + g];

  #pragma unroll
  for (int k = 0; k < 2; k++) {
    // ---- weights + 3 column byte-offsets (fp16 layout) ----
    float tn = c.w * (1.0f / 99.0f);
    float gy = 2.0f * tn - 1.0f;
    float iy = ((gy + 1.0f) * 0.5f) * 99.0f;
    float y0f = floorf(iy);
    float wy1 = iy - y0f;
    int row; float wy;
    if (wy1 > 0.5f) { row = (int)y0f + 1; wy = wy1; }
    else            { row = (int)y0f;     wy = 1.0f - wy1; }
    row = min(max(row, 0), NFRAMES - 1);
    float wy3 = wy * wy * wy;
    const unsigned rowbyte = ((unsigned)row << 15) + ((unsigned)sl << 4);
    float wx[3]; unsigned cb[3];
    { float gx = 2.0f * c.x - 1.0f; float ix = ((gx + 1.0f) * 0.5f) * 255.0f;
      float x0f = floorf(ix); wx[0] = ix - x0f;
      cb[0] = rowbyte + ((unsigned)(int)x0f << 7); }
    { float gx = 2.0f * c.y - 1.0f; float ix = ((gx + 1.0f) * 0.5f) * 255.0f;
      float x0f = floorf(ix); wx[1] = ix - x0f;
      cb[1] = rowbyte + ((unsigned)(int)x0f << 7); }
    { float gx = 2.0f * c.z - 1.0f; float ix = ((gx + 1.0f) * 0.5f) * 255.0f;
      float x0f = floorf(ix); wx[2] = ix - x0f;
      cb[2] = rowbyte + ((unsigned)(int)x0f << 7); }

    // ---- 18 row loads (x0 and x0+1 rows per plane) ----
    U16x8 v0[9], v1[9];
    #pragma unroll
    for (int ss = 0; ss < 9; ss++) {
      const char* bp = Tb + (size_t)ss * T2PLANE_B;
      unsigned cbs = cb[ss % 3];
      v0[ss].u = *(const uint4*)(bp + cbs);
      v1[ss].u = *(const uint4*)(bp + cbs + 128);
    }
    float4 c_nxt = c;
    if (k < 1) c_nxt = xs4[base + 8 + g];
    __builtin_amdgcn_sched_barrier(0);     // pin the load batch above

    // ---- consume: fma_mix lerp (f32 math, f16 srcs), product, 8-reduce ----
    float dsum[3];
    #pragma unroll
    for (int f = 0; f < 3; f++) {
      float pr[8];
      #pragma unroll
      for (int pl = 0; pl < 3; pl++) {
        int ss = f * 3 + pl;
        float w1 = wx[pl];
        float w0 = 1.0f - w1;
        #pragma unroll
        for (int dw = 0; dw < 4; dw++) {
          unsigned ad = v0[ss].d[dw];
          unsigned bd = v1[ss].d[dw];
          float slo = fma_mix_lo(ad, w0, fma_mix_lo(bd, w1, 0.0f));
          float shi = fma_mix_hi(ad, w0, fma_mix_hi(bd, w1, 0.0f));
          if (pl == 0) { pr[2 * dw] = slo;  pr[2 * dw + 1] = shi; }
          else         { pr[2 * dw] *= slo; pr[2 * dw + 1] *= shi; }
        }
      }
      float r = (((pr[0] + pr[1]) + (pr[2] + pr[3])) +
                 ((pr[4] + pr[5]) + (pr[6] + pr[7]))) * wy3;
      #pragma unroll
      for (int m = 4; m > 0; m >>= 1) r += __shfl_xor(r, m, 64);  // 8-group
      dsum[f] = r;
    }

    float px = c.x + dsum[0];
    float py = c.y + dsum[1];
    float pz = c.z + dsum[2];

    // ---- PE + store: 8 rounds, one point each (coalesced 252 B store) ----
    #pragma unroll
    for (int q2 = 0; q2 < 8; q2++) {
      float qx = __shfl(px, q2 * 8, 64);
      float qy = __shfl(py, q2 * 8, 64);
      float qz = __shfl(pz, q2 * 8, 64);
      int pq = __shfl(permv, k * 8 + q2, 64);
      float pd = (dd == 0) ? qx : (dd == 1) ? qy : qz;
      float val = hw_sin_rev(pd * scale * inv2pi + cosoff);
      if (lane == 0) val = qx;
      else if (lane == 1) val = qy;
      else if (lane == 2) val = qz;
      if (lane < 63)
        __builtin_nontemporal_store(val, &out[(size_t)pq * 63 + lane]);
    }

    c = c_nxt;
  }
}

// ---- fallback (ws fits f32 T only): 2-pt/wave, float2 channel pairs ----
__global__ __launch_bounds__(256) void sample2_k(const float* __restrict__ xin,
                                                 const float* __restrict__ T,
                                                 float* __restrict__ out) {
  const int lane = threadIdx.x & 63;
  const int half = lane >> 5;
  const int l = lane & 31;
  const int wave = blockIdx.x * 4 + (threadIdx.x >> 6);
  const int nW = gridDim.x * 4;
  const int j = (lane >= 3) ? (lane - 3) : 0;
  const int fq = j / 6;
  const int rr = j - fq * 6;
  const int isc = rr / 3;
  const int dd = rr - isc * 3;
  const float scale = (float)(1 << fq);
  const float cosoff = isc ? 0.25f : 0.0f;
  const float inv2pi = 0.15915493667125702f;
  const float4* __restrict__ x4 = (const float4*)xin;

  for (int base = wave * 2; base < P_N; base += nW * 2) {
    const int p = base + half;
    float4 c = x4[p];
    float tn = c.w / 99.0f;
    float gy = 2.0f * tn - 1.0f;
    float iy = ((gy + 1.0f) * 0.5f) * 99.0f;
    float y0f = floorf(iy);
    float wy1 = iy - y0f;
    int row; float wy;
    if (wy1 > 0.5f) { row = (int)y0f + 1; wy = wy1; }
    else            { row = (int)y0f;     wy = 1.0f - wy1; }
    row = min(max(row, 0), NFRAMES - 1);
    const int rowoff = row * TROW;
    float dsum[3];
    float crd[3] = {c.x, c.y, c.z};
    #pragma unroll
    for (int f = 0; f < 3; f++) {
      float prx, pry;
      #pragma unroll
      for (int pl = 0; pl < 3; pl++) {
        float gx = 2.0f * crd[pl] - 1.0f;
        float ix = ((gx + 1.0f) * 0.5f) * 255.0f;
        float x0f = floorf(ix);
        float wx1 = ix - x0f;
        float wx0 = 1.0f - wx1;
        int x0 = (int)x0f;
        const float2* rp = (const float2*)(T + (size_t)(f * 3 + pl) * TPLANE
                                             + (size_t)(rowoff + x0 * CHAN_));
        float2 v0 = rp[l];
        float2 v1 = rp[l + 32];
        float sx = (v0.x * wx0 + v1.x * wx1) * wy;
        float sy = (v0.y * wx0 + v1.y * wx1) * wy;
        if (pl == 0) { prx = sx; pry = sy; }
        else         { prx *= sx; pry *= sy; }
      }
      float r = prx + pry;
      #pragma unroll
      for (int m = 16; m > 0; m >>= 1) r += __shfl_xor(r, m, 64);
      dsum[f] = r;
    }
    float px = c.x + dsum[0];
    float py = c.y + dsum[1];
    float pz = c.z + dsum[2];
    #pragma unroll
    for (int qq = 0; qq < 2; qq++) {
      float qx = __shfl(px, qq * 32, 64);
      float qy = __shfl(py, qq * 32, 64);
      float qz = __shfl(pz, qq * 32, 64);
      float pd = (dd == 0) ? qx : (dd == 1) ? qy : qz;
      float val = hw_sin_rev(pd * scale * inv2pi + cosoff);
      if (lane == 0) val = qx;
      else if (lane == 1) val = qy;
      else if (lane == 2) val = qz;
      if (lane < 63) out[(size_t)(base + qq) * 63 + lane] = val;
    }
  }
}

// ---- fallback (no usable ws): direct-layout sampler ----
__global__ __launch_bounds__(256) void sample_fb_k(const float* __restrict__ xin,
                                                   const float* __restrict__ f0,
                                                   const float* __restrict__ f1,
                                                   const float* __restrict__ f2,
                                                   float* __restrict__ out) {
  const int lane = threadIdx.x & 63;
  int wave = blockIdx.x * 4 + (threadIdx.x >> 6);
  const int nW = gridDim.x * 4;
  for (int p = wave; p < P_N; p += nW) {
    float cx = xin[(size_t)p * 4 + 0];
    float cy = xin[(size_t)p * 4 + 1];
    float cz = xin[(size_t)p * 4 + 2];
    float ct = xin[(size_t)p * 4 + 3];
    float tn = ct / 99.0f;
    float gy = 2.0f * tn - 1.0f;
    float iy = ((gy + 1.0f) * 0.5f) * 99.0f;
    float y0f = floorf(iy);
    float wy1 = iy - y0f;
    float wy0 = 1.0f - wy1;
    int y0 = (int)y0f, y1 = y0 + 1;
    bool y0in = (unsigned)y0 < (unsigned)NFRAMES;
    bool y1in = (unsigned)y1 < (unsigned)NFRAMES;
    int y0c = min(max(y0, 0), NFRAMES - 1);
    int y1c = min(max(y1, 0), NFRAMES - 1);
    float d[3];
    #pragma unroll
    for (int f = 0; f < 3; f++) {
      float prodc;
      #pragma unroll
      for (int pl = 0; pl < 3; pl++) {
        float coord = (pl == 0) ? cx : (pl == 1) ? cy : cz;
        float gx = 2.0f * coord - 1.0f;
        float ix = ((gx + 1.0f) * 0.5f) * 255.0f;
        float x0f = floorf(ix);
        float wx1 = ix - x0f;
        float wx0 = 1.0f - wx1;
        int x0 = (int)x0f, x1 = x0 + 1;
        int x0c = min(max(x0, 0), RESO_ - 1);
        int x1c = min(max(x1, 0), RESO_ - 1);
        const float* ff = (f == 0) ? f0 : (f == 1) ? f1 : f2;
        const float* bse = ff + ((size_t)pl * CHAN_ + lane) * (NFRAMES * RESO_);
        float v00 = y0in ? bse[(size_t)y0c * RESO_ + x0c] : 0.0f;
        float v01 = y0in ? bse[(size_t)y0c * RESO_ + x1c] : 0.0f;
        float v10 = y1in ? bse[(size_t)y1c * RESO_ + x0c] : 0.0f;
        float v11 = y1in ? bse[(size_t)y1c * RESO_ + x1c] : 0.0f;
        float ss2 = v00 * (wy0 * wx0) + v01 * (wy0 * wx1) + v10 * (wy1 * wx0) + v11 * (wy1 * wx1);
        prodc = (pl == 0) ? ss2 : prodc * ss2;
      }
      float sum = prodc;
      #pragma unroll
      for (int o = 32; o > 0; o >>= 1) sum += __shfl_xor(sum, o, 64);
      d[f] = sum;
    }
    float p0 = cx + d[0], p1 = cy + d[1], p2 = cz + d[2];
    if (lane < 63) {
      float val;
      if (lane == 0) val = p0;
      else if (lane == 1) val = p1;
      else if (lane == 2) val = p2;
      else {
        int jj = lane - 3;
        int fq2 = jj / 6;
        int r2 = jj - fq2 * 6;
        int s2 = r2 / 3;
        int d2 = r2 - s2 * 3;
        float pd = (d2 == 0) ? p0 : (d2 == 1) ? p1 : p2;
        float ang = pd * (float)(1 << fq2);
        val = (s2 == 0) ? sinf(ang) : cosf(ang);
      }
      out[(size_t)p * 63 + lane] = val;
    }
  }
}

extern "C" void kernel_launch(void* const* d_in, const int* in_sizes, int n_in,
                              void* d_out, int out_size, void* d_ws, size_t ws_size,
                              hipStream_t stream) {
  const float* x  = (const float*)d_in[0];
  const float* f0 = (const float*)d_in[1];
  const float* f1 = (const float*)d_in[2];
  const float* f2 = (const float*)d_in[3];
  float* out = (float*)d_out;

  const size_t szT2   = (size_t)9 * T2PLANE_B;                  // ~29.5 MB
  const size_t szT    = (size_t)9 * TPLANE * sizeof(float);     // ~59 MB
  const size_t szPerm = (size_t)P_N * sizeof(int);              // 2 MB
  const size_t szXs   = (size_t)P_N * sizeof(float4);           // 8 MB

  if (ws_size >= szT2 + szPerm + szXs) {
    _Float16* T2 = (_Float16*)d_ws;
    int* perm    = (int*)((char*)d_ws + szT2);
    float4* xs4  = (float4*)((char*)d_ws + szT2 + szPerm);
    prep5_k<_Float16, true><<<dim3(NSUBS + NTRB), dim3(256), 0, stream>>>(
        f0, f1, f2, T2, x, perm, xs4);
    sample8h_k<<<dim3(8192), dim3(256), 0, stream>>>(xs4, T2, perm, out);
  } else if (ws_size >= szT) {
    float* T = (float*)d_ws;
    prep5_k<float, false><<<dim3(NSUBS + NTRB), dim3(256), 0, stream>>>(
        f0, f1, f2, T, x, nullptr, nullptr);
    sample2_k<<<dim3(4096), dim3(256), 0, stream>>>(x, T, out);
  } else {
    sample_fb_k<<<dim3(8192), dim3(256), 0, stream>>>(x, f0, f1, f2, out);
  }
}

// Round 16
// 115.287 us; speedup vs baseline: 2.2123x; 1.0232x over previous
//
#include <hip/hip_runtime.h>
#include <math.h>

#define P_N 524288
#define NFRAMES 100
#define RESO_ 256
#define CHAN_ 64
#define NFREQ 10

// f32 transposed layout (fallback tiers): T[(f*3+pl)][t][x][c]
#define TROW   (RESO_ * CHAN_)          // 16384 floats per t-row
#define TPLANE (NFRAMES * TROW)         // 1,638,400 floats per plane

// fp16 transposed layout (main tier): row = 64 ch * 2B = 128 B = 1 line
#define T2PLANE_B ((size_t)NFRAMES * RESO_ * CHAN_ * 2)   // 3,276,800 B

#define NSUBS 64                        // independent sort blocks
#define SUBSZ (P_N / NSUBS)             // 8192 points per sub
#define NTRB  (3 * 3 * NFRAMES * 4)     // 3600 transpose blocks

// ---------------- fused prep: 64 per-sub LDS counting-sorts + transpose ----
// Sort key = t only (R10: the (t,x) compound key was NULL for sample time;
// t-only needs 104 ints of LDS -> transpose co-residency back to ~8/CU).
// Transpose: float4 reads (1024 B/wave-instr), packed 8B writes.
template <typename TO, bool WXS>
__global__ __launch_bounds__(256) void prep6_k(const float* __restrict__ f0,
                                               const float* __restrict__ f1,
                                               const float* __restrict__ f2,
                                               TO* __restrict__ T,
                                               const float* __restrict__ xin,
                                               int* __restrict__ perm,
                                               float4* __restrict__ xs4) {
  __shared__ float tile[64][65];
  __shared__ int histS[104];

  if (blockIdx.x < NSUBS) {
    if (perm == nullptr) return;
    const int s = blockIdx.x;
    const float4* __restrict__ x4 = (const float4*)xin;
    for (int i = threadIdx.x; i < 104; i += 256) histS[i] = 0;
    __syncthreads();
    for (int i = threadIdx.x; i < SUBSZ; i += 256) {
      float tw = x4[(size_t)s * SUBSZ + i].w;
      int t = min(max((int)tw, 0), NFRAMES - 1);
      atomicAdd(&histS[t], 1);
    }
    __syncthreads();
    if (threadIdx.x == 0) {
      int run = 0;
      for (int t = 0; t < NFRAMES; t++) { int v = histS[t]; histS[t] = run; run += v; }
    }
    __syncthreads();
    for (int i = threadIdx.x; i < SUBSZ; i += 256) {
      float4 v = x4[(size_t)s * SUBSZ + i];
      int t = min(max((int)v.w, 0), NFRAMES - 1);
      int pos = s * SUBSZ + atomicAdd(&histS[t], 1);
      perm[pos] = s * SUBSZ + i;
      if (WXS) xs4[pos] = v;
    }
    return;
  }

  // ---- transpose blocks ----
  int b = blockIdx.x - NSUBS;
  int xblk = b & 3; b >>= 2;                 // 4 x-tiles of 64
  int t = b % NFRAMES; b /= NFRAMES;
  int pl = b % 3; int f = b / 3;
  const float* src = (f == 0 ? f0 : (f == 1 ? f1 : f2)) + (size_t)pl * CHAN_ * NFRAMES * RESO_;
  const int tid = threadIdx.x;

  // phase 1: float4 reads; thread covers (cc, xq*4..xq*4+3)
  {
    const int xq = tid & 15;              // 16 quads cover 64 x
    const int c0 = tid >> 4;              // 16 rows per pass
    #pragma unroll
    for (int p = 0; p < 4; p++) {
      int cc = p * 16 + c0;
      const float4* sp = (const float4*)(src + (size_t)cc * (NFRAMES * RESO_)
                                             + (size_t)t * RESO_ + xblk * 64);
      float4 v = sp[xq];
      tile[cc][xq * 4 + 0] = v.x;
      tile[cc][xq * 4 + 1] = v.y;
      tile[cc][xq * 4 + 2] = v.z;
      tile[cc][xq * 4 + 3] = v.w;
    }
  }
  __syncthreads();
  // phase 2: packed writes; thread covers (xx, cq*4..cq*4+3)
  {
    const int cq = tid & 15;              // 16 quads cover 64 c
    const int x0 = tid >> 4;
    #pragma unroll
    for (int p = 0; p < 4; p++) {
      int xx = p * 16 + x0;
      float t0 = tile[cq * 4 + 0][xx];
      float t1 = tile[cq * 4 + 1][xx];
      float t2 = tile[cq * 4 + 2][xx];
      float t3 = tile[cq * 4 + 3][xx];
      TO* dst = T + (((size_t)(f * 3 + pl) * NFRAMES + t) * RESO_
                     + (size_t)(xblk * 64 + xx)) * CHAN_ + cq * 4;
      if constexpr (sizeof(TO) == 2) {
        union { _Float16 h[4]; uint2 u; } pk;
        pk.h[0] = (_Float16)t0; pk.h[1] = (_Float16)t1;
        pk.h[2] = (_Float16)t2; pk.h[3] = (_Float16)t3;
        *(uint2*)dst = pk.u;
      } else {
        float4 pv = {t0, t1, t2, t3};
        *(float4*)dst = pv;
      }
    }
  }
}

__device__ __forceinline__ float hw_sin_rev(float rev) {
  float r, s;
  asm("v_fract_f32 %0, %1" : "=v"(r) : "v"(rev));
  asm("v_sin_f32 %0, %1" : "=v"(s) : "v"(r));
  return s;
}

// f32 = f16(lo/hi half of packed dword) * f32 + f32 — f32 math, no cvt
__device__ __forceinline__ float fma_mix_lo(unsigned h2, float b, float c) {
  float d;
  asm("v_fma_mix_f32 %0, %1, %2, %3 op_sel:[0,0,0] op_sel_hi:[1,0,0]"
      : "=v"(d) : "v"(h2), "v"(b), "v"(c));
  return d;
}
__device__ __forceinline__ float fma_mix_hi(unsigned h2, float b, float c) {
  float d;
  asm("v_fma_mix_f32 %0, %1, %2, %3 op_sel:[1,0,0] op_sel_hi:[1,0,0]"
      : "=v"(d) : "v"(h2), "v"(b), "v"(c));
  return d;
}

union U16x8 { uint4 u; unsigned d[4]; };

// 8 points per wave iteration, 16 points per wave (2 iters); 8192 blocks.
// Each 8-lane group loads a full 64-ch fp16 row as uint4 (128 B = 1 line).
// Lerp via v_fma_mix_f32; PE/store = broadcast structure (coalesced 252 B).
__global__ __launch_bounds__(256) void sample8h_k(const float4* __restrict__ xs4,
                                                  const _Float16* __restrict__ T,
                                                  const int* __restrict__ perm,
                                                  float* __restrict__ out) {
  const int lane = threadIdx.x & 63;
  const int g = lane >> 3;          // group 0..7
  const int sl = lane & 7;          // sub-lane in group
  const int b = blockIdx.x;         // 8192 blocks
  const int wix = (b >> 3) * 4 + (threadIdx.x >> 6);   // 0..4095 within XCD
  const int q = (b & 7) * 64 + (wix >> 6);             // chunk 0..511 (~t)
  const int s = wix & 63;                              // sub 0..63
  const int base = s * SUBSZ + q * 16;                 // 16 points per wave

  // per-lane PE constants (output element id = lane, valid for lane<63)
  const int j = (lane >= 3) ? (lane - 3) : 0;
  const int fq = j / 6;
  const int rr = j - fq * 6;
  const int isc = rr / 3;
  const int dd = rr - isc * 3;
  const float scale = (float)(1 << fq);
  const float cosoff = isc ? 0.25f : 0.0f;
  const float inv2pi = 0.15915493667125702f;

  const char* Tb = (const char*)T;
  const int permv = perm[base + (lane & 15)];

  float4 c = xs4[base + g];

  #pragma unroll
  for (int k = 0; k < 2; k++) {
    // ---- weights + 3 column byte-offsets (fp16 layout) ----
    float tn = c.w * (1.0f / 99.0f);
    float gy = 2.0f * tn - 1.0f;
    float iy = ((gy + 1.0f) * 0.5f) * 99.0f;
    float y0f = floorf(iy);
    float wy1 = iy - y0f;
    int row; float wy;
    if (wy1 > 0.5f) { row = (int)y0f + 1; wy = wy1; }
    else            { row = (int)y0f;     wy = 1.0f - wy1; }
    row = min(max(row, 0), NFRAMES - 1);
    float wy3 = wy * wy * wy;
    const unsigned rowbyte = ((unsigned)row << 15) + ((unsigned)sl << 4);
    float wx[3]; unsigned cb[3];
    { float gx = 2.0f * c.x - 1.0f; float ix = ((gx + 1.0f) * 0.5f) * 255.0f;
      float x0f = floorf(ix); wx[0] = ix - x0f;
      cb[0] = rowbyte + ((unsigned)(int)x0f << 7); }
    { float gx = 2.0f * c.y - 1.0f; float ix = ((gx + 1.0f) * 0.5f) * 255.0f;
      float x0f = floorf(ix); wx[1] = ix - x0f;
      cb[1] = rowbyte + ((unsigned)(int)x0f << 7); }
    { float gx = 2.0f * c.z - 1.0f; float ix = ((gx + 1.0f) * 0.5f) * 255.0f;
      float x0f = floorf(ix); wx[2] = ix - x0f;
      cb[2] = rowbyte + ((unsigned)(int)x0f << 7); }

    // ---- 18 row loads (x0 and x0+1 rows per plane) ----
    U16x8 v0[9], v1[9];
    #pragma unroll
    for (int ss = 0; ss < 9; ss++) {
      const char* bp = Tb + (size_t)ss * T2PLANE_B;
      unsigned cbs = cb[ss % 3];
      v0[ss].u = *(const uint4*)(bp + cbs);
      v1[ss].u = *(const uint4*)(bp + cbs + 128);
    }
    float4 c_nxt = c;
    if (k < 1) c_nxt = xs4[base + 8 + g];
    __builtin_amdgcn_sched_barrier(0);     // pin the load batch above

    // ---- consume: fma_mix lerp (f32 math, f16 srcs), product, 8-reduce ----
    float dsum[3];
    #pragma unroll
    for (int f = 0; f < 3; f++) {
      float pr[8];
      #pragma unroll
      for (int pl = 0; pl < 3; pl++) {
        int ss = f * 3 + pl;
        float w1 = wx[pl];
        float w0 = 1.0f - w1;
        #pragma unroll
        for (int dw = 0; dw < 4; dw++) {
          unsigned ad = v0[ss].d[dw];
          unsigned bd = v1[ss].d[dw];
          float slo = fma_mix_lo(ad, w0, fma_mix_lo(bd, w1, 0.0f));
          float shi = fma_mix_hi(ad, w0, fma_mix_hi(bd, w1, 0.0f));
          if (pl == 0) { pr[2 * dw] = slo;  pr[2 * dw + 1] = shi; }
          else         { pr[2 * dw] *= slo; pr[2 * dw + 1] *= shi; }
        }
      }
      float r = (((pr[0] + pr[1]) + (pr[2] + pr[3])) +
                 ((pr[4] + pr[5]) + (pr[6] + pr[7]))) * wy3;
      #pragma unroll
      for (int m = 4; m > 0; m >>= 1) r += __shfl_xor(r, m, 64);  // 8-group
      dsum[f] = r;
    }

    float px = c.x + dsum[0];
    float py = c.y + dsum[1];
    float pz = c.z + dsum[2];

    // ---- PE + store: 8 rounds, one point each (coalesced 252 B store) ----
    #pragma unroll
    for (int q2 = 0; q2 < 8; q2++) {
      float qx = __shfl(px, q2 * 8, 64);
      float qy = __shfl(py, q2 * 8, 64);
      float qz = __shfl(pz, q2 * 8, 64);
      int pq = __shfl(permv, k * 8 + q2, 64);
      float pd = (dd == 0) ? qx : (dd == 1) ? qy : qz;
      float val = hw_sin_rev(pd * scale * inv2pi + cosoff);
      if (lane == 0) val = qx;
      else if (lane == 1) val = qy;
      else if (lane == 2) val = qz;
      if (lane < 63)
        __builtin_nontemporal_store(val, &out[(size_t)pq * 63 + lane]);
    }

    c = c_nxt;
  }
}

// ---- fallback (ws fits f32 T only): 2-pt/wave, float2 channel pairs ----
__global__ __launch_bounds__(256) void sample2_k(const float* __restrict__ xin,
                                                 const float* __restrict__ T,
                                                 float* __restrict__ out) {
  const int lane = threadIdx.x & 63;
  const int half = lane >> 5;
  const int l = lane & 31;
  const int wave = blockIdx.x * 4 + (threadIdx.x >> 6);
  const int nW = gridDim.x * 4;
  const int j = (lane >= 3) ? (lane - 3) : 0;
  const int fq = j / 6;
  const int rr = j - fq * 6;
  const int isc = rr / 3;
  const int dd = rr - isc * 3;
  const float scale = (float)(1 << fq);
  const float cosoff = isc ? 0.25f : 0.0f;
  const float inv2pi = 0.15915493667125702f;
  const float4* __restrict__ x4 = (const float4*)xin;

  for (int base = wave * 2; base < P_N; base += nW * 2) {
    const int p = base + half;
    float4 c = x4[p];
    float tn = c.w / 99.0f;
    float gy = 2.0f * tn - 1.0f;
    float iy = ((gy + 1.0f) * 0.5f) * 99.0f;
    float y0f = floorf(iy);
    float wy1 = iy - y0f;
    int row; float wy;
    if (wy1 > 0.5f) { row = (int)y0f + 1; wy = wy1; }
    else            { row = (int)y0f;     wy = 1.0f - wy1; }
    row = min(max(row, 0), NFRAMES - 1);
    const int rowoff = row * TROW;
    float dsum[3];
    float crd[3] = {c.x, c.y, c.z};
    #pragma unroll
    for (int f = 0; f < 3; f++) {
      float prx, pry;
      #pragma unroll
      for (int pl = 0; pl < 3; pl++) {
        float gx = 2.0f * crd[pl] - 1.0f;
        float ix = ((gx + 1.0f) * 0.5f) * 255.0f;
        float x0f = floorf(ix);
        float wx1 = ix - x0f;
        float wx0 = 1.0f - wx1;
        int x0 = (int)x0f;
        const float2* rp = (const float2*)(T + (size_t)(f * 3 + pl) * TPLANE
                                             + (size_t)(rowoff + x0 * CHAN_));
        float2 v0 = rp[l];
        float2 v1 = rp[l + 32];
        float sx = (v0.x * wx0 + v1.x * wx1) * wy;
        float sy = (v0.y * wx0 + v1.y * wx1) * wy;
        if (pl == 0) { prx = sx; pry = sy; }
        else         { prx *= sx; pry *= sy; }
      }
      float r = prx + pry;
      #pragma unroll
      for (int m = 16; m > 0; m >>= 1) r += __shfl_xor(r, m, 64);
      dsum[f] = r;
    }
    float px = c.x + dsum[0];
    float py = c.y + dsum[1];
    float pz = c.z + dsum[2];
    #pragma unroll
    for (int qq = 0; qq < 2; qq++) {
      float qx = __shfl(px, qq * 32, 64);
      float qy = __shfl(py, qq * 32, 64);
      float qz = __shfl(pz, qq * 32, 64);
      float pd = (dd == 0) ? qx : (dd == 1) ? qy : qz;
      float val = hw_sin_rev(pd * scale * inv2pi + cosoff);
      if (lane == 0) val = qx;
      else if (lane == 1) val = qy;
      else if (lane == 2) val = qz;
      if (lane < 63) out[(size_t)(base + qq) * 63 + lane] = val;
    }
  }
}

// ---- fallback (no usable ws): direct-layout sampler ----
__global__ __launch_bounds__(256) void sample_fb_k(const float* __restrict__ xin,
                                                   const float* __restrict__ f0,
                                                   const float* __restrict__ f1,
                                                   const float* __restrict__ f2,
                                                   float* __restrict__ out) {
  const int lane = threadIdx.x & 63;
  int wave = blockIdx.x * 4 + (threadIdx.x >> 6);
  const int nW = gridDim.x * 4;
  for (int p = wave; p < P_N; p += nW) {
    float cx = xin[(size_t)p * 4 + 0];
    float cy = xin[(size_t)p * 4 + 1];
    float cz = xin[(size_t)p * 4 + 2];
    float ct = xin[(size_t)p * 4 + 3];
    float tn = ct / 99.0f;
    float gy = 2.0f * tn - 1.0f;
    float iy = ((gy + 1.0f) * 0.5f) * 99.0f;
    float y0f = floorf(iy);
    float wy1 = iy - y0f;
    float wy0 = 1.0f - wy1;
    int y0 = (int)y0f, y1 = y0 + 1;
    bool y0in = (unsigned)y0 < (unsigned)NFRAMES;
    bool y1in = (unsigned)y1 < (unsigned)NFRAMES;
    int y0c = min(max(y0, 0), NFRAMES - 1);
    int y1c = min(max(y1, 0), NFRAMES - 1);
    float d[3];
    #pragma unroll
    for (int f = 0; f < 3; f++) {
      float prodc;
      #pragma unroll
      for (int pl = 0; pl < 3; pl++) {
        float coord = (pl == 0) ? cx : (pl == 1) ? cy : cz;
        float gx = 2.0f * coord - 1.0f;
        float ix = ((gx + 1.0f) * 0.5f) * 255.0f;
        float x0f = floorf(ix);
        float wx1 = ix - x0f;
        float wx0 = 1.0f - wx1;
        int x0 = (int)x0f, x1 = x0 + 1;
        int x0c = min(max(x0, 0), RESO_ - 1);
        int x1c = min(max(x1, 0), RESO_ - 1);
        const float* ff = (f == 0) ? f0 : (f == 1) ? f1 : f2;
        const float* bse = ff + ((size_t)pl * CHAN_ + lane) * (NFRAMES * RESO_);
        float v00 = y0in ? bse[(size_t)y0c * RESO_ + x0c] : 0.0f;
        float v01 = y0in ? bse[(size_t)y0c * RESO_ + x1c] : 0.0f;
        float v10 = y1in ? bse[(size_t)y1c * RESO_ + x0c] : 0.0f;
        float v11 = y1in ? bse[(size_t)y1c * RESO_ + x1c] : 0.0f;
        float ss2 = v00 * (wy0 * wx0) + v01 * (wy0 * wx1) + v10 * (wy1 * wx0) + v11 * (wy1 * wx1);
        prodc = (pl == 0) ? ss2 : prodc * ss2;
      }
      float sum = prodc;
      #pragma unroll
      for (int o = 32; o > 0; o >>= 1) sum += __shfl_xor(sum, o, 64);
      d[f] = sum;
    }
    float p0 = cx + d[0], p1 = cy + d[1], p2 = cz + d[2];
    if (lane < 63) {
      float val;
      if (lane == 0) val = p0;
      else if (lane == 1) val = p1;
      else if (lane == 2) val = p2;
      else {
        int jj = lane - 3;
        int fq2 = jj / 6;
        int r2 = jj - fq2 * 6;
        int s2 = r2 / 3;
        int d2 = r2 - s2 * 3;
        float pd = (d2 == 0) ? p0 : (d2 == 1) ? p1 : p2;
        float ang = pd * (float)(1 << fq2);
        val = (s2 == 0) ? sinf(ang) : cosf(ang);
      }
      out[(size_t)p * 63 + lane] = val;
    }
  }
}

extern "C" void kernel_launch(void* const* d_in, const int* in_sizes, int n_in,
                              void* d_out, int out_size, void* d_ws, size_t ws_size,
                              hipStream_t stream) {
  const float* x  = (const float*)d_in[0];
  const float* f0 = (const float*)d_in[1];
  const float* f1 = (const float*)d_in[2];
  const float* f2 = (const float*)d_in[3];
  float* out = (float*)d_out;

  const size_t szT2   = (size_t)9 * T2PLANE_B;                  // ~29.5 MB
  const size_t szT    = (size_t)9 * TPLANE * sizeof(float);     // ~59 MB
  const size_t szPerm = (size_t)P_N * sizeof(int);              // 2 MB
  const size_t szXs   = (size_t)P_N * sizeof(float4);           // 8 MB

  if (ws_size >= szT2 + szPerm + szXs) {
    _Float16* T2 = (_Float16*)d_ws;
    int* perm    = (int*)((char*)d_ws + szT2);
    float4* xs4  = (float4*)((char*)d_ws + szT2 + szPerm);
    prep6_k<_Float16, true><<<dim3(NSUBS + NTRB), dim3(256), 0, stream>>>(
        f0, f1, f2, T2, x, perm, xs4);
    sample8h_k<<<dim3(8192), dim3(256), 0, stream>>>(xs4, T2, perm, out);
  } else if (ws_size >= szT) {
    float* T = (float*)d_ws;
    prep6_k<float, false><<<dim3(NSUBS + NTRB), dim3(256), 0, stream>>>(
        f0, f1, f2, T, x, nullptr, nullptr);
    sample2_k<<<dim3(4096), dim3(256), 0, stream>>>(x, T, out);
  } else {
    sample_fb_k<<<dim3(8192), dim3(256), 0, stream>>>(x, f0, f1, f2, out);
  }
}